// Round 4
// baseline (120.608 us; speedup 1.0000x reference)
//
#include <hip/hip_runtime.h>
#include <hip/hip_bf16.h>

// N=2048, D=768, H=12, Y=64. W = [Wq;Wk] as [1536][768].
#define NN 2048
#define DD 768
#define HH 12
#define HW 1536
#define G_ELEMS (NN*DD)           // 1572864
#define W1_ELEMS (HH*64*DD)       // 589824
#define SPLITS 4
#define KPW (NN/SPLITS)           // 512 k-rows per split

typedef __attribute__((ext_vector_type(8))) short bf16x8;
typedef __attribute__((ext_vector_type(4))) float f32x4;

// native v_exp_f32 / v_log_f32 (both base-2). __exp2f/__log2f collide with
// glibc math.h reserved identifiers under -x hip.
__device__ __forceinline__ float exp2g(float x) { return __builtin_amdgcn_exp2f(x); }
__device__ __forceinline__ float log2g(float x) { return __builtin_amdgcn_logf(x); }

// ---------------- Kernel 1: fp32 -> bf16 convert -----------------------------
// Fold beta*log2(e) = 0.125*1.4426950408889634 into Wq so scores are in
// base-2 units and exp2g needs no pre-multiply.
#define QSCALE 0.18033688011112042f
__global__ __launch_bounds__(256) void convert_kernel(
    const float* __restrict__ g, const float* __restrict__ Wq,
    const float* __restrict__ Wk, __hip_bfloat16* __restrict__ gB,
    __hip_bfloat16* __restrict__ wB) {
  int base = (blockIdx.x * 256 + threadIdx.x) * 4;
  float4 v;
  __hip_bfloat16* dst;
  if (base < G_ELEMS) {
    v = *reinterpret_cast<const float4*>(g + base);
    dst = gB + base;
  } else if (base < G_ELEMS + W1_ELEMS) {
    int o = base - G_ELEMS;
    v = *reinterpret_cast<const float4*>(Wq + o);
    v.x *= QSCALE; v.y *= QSCALE; v.z *= QSCALE; v.w *= QSCALE;
    dst = wB + o;
  } else {
    int o = base - (G_ELEMS + W1_ELEMS);
    v = *reinterpret_cast<const float4*>(Wk + o);
    dst = wB + W1_ELEMS + o;
  }
  __hip_bfloat16 h0 = __float2bfloat16(v.x), h1 = __float2bfloat16(v.y);
  __hip_bfloat16 h2 = __float2bfloat16(v.z), h3 = __float2bfloat16(v.w);
  ushort4 u;
  u.x = *reinterpret_cast<unsigned short*>(&h0);
  u.y = *reinterpret_cast<unsigned short*>(&h1);
  u.z = *reinterpret_cast<unsigned short*>(&h2);
  u.w = *reinterpret_cast<unsigned short*>(&h3);
  *reinterpret_cast<ushort4*>(dst) = u;
}

// ---------------- Kernel 2: QK projection GEMM (bf16 MFMA) -------------------
// C[2048][1536] = gB[2048][768] * wB[1536][768]^T
// 64x64 tile, BK=64, grid (32,24)=768 blocks (3/CU). 4 waves in 2x2, each
// computes 32x32 as 2x2 frags of 16x16x32.
#define LDP 72   // 64 + 8 pad -> 2-way max on frag reads (free, m136)
__global__ __launch_bounds__(256) void proj_kernel(
    const __hip_bfloat16* __restrict__ gB, const __hip_bfloat16* __restrict__ wB,
    __hip_bfloat16* __restrict__ QK) {
  __shared__ __align__(16) __hip_bfloat16 As[64 * LDP];
  __shared__ __align__(16) __hip_bfloat16 Bs[64 * LDP];
  const int t = threadIdx.x;
  const int wave = t >> 6, lane = t & 63;
  const int lr = lane & 15, lg = lane >> 4;
  const int wm = wave & 1, wn = wave >> 1;
  const int bm = blockIdx.x, bn = blockIdx.y;

  f32x4 acc[2][2] = {};

  for (int kt = 0; kt < DD; kt += 64) {
    __syncthreads();
#pragma unroll
    for (int i = 0; i < 2; ++i) {
      int c = t + i * 256;                 // 512 chunks of 8 bf16
      int row = c >> 3, seg = (c & 7) * 8;
      uint4 va = *reinterpret_cast<const uint4*>(gB + (bm * 64 + row) * DD + kt + seg);
      *reinterpret_cast<uint4*>(&As[row * LDP + seg]) = va;
      uint4 vb = *reinterpret_cast<const uint4*>(wB + (bn * 64 + row) * DD + kt + seg);
      *reinterpret_cast<uint4*>(&Bs[row * LDP + seg]) = vb;
    }
    __syncthreads();
#pragma unroll
    for (int ks = 0; ks < 2; ++ks) {
      bf16x8 a[2], b[2];
#pragma unroll
      for (int mt = 0; mt < 2; ++mt)
        a[mt] = *reinterpret_cast<const bf16x8*>(&As[(wm * 32 + mt * 16 + lr) * LDP + ks * 32 + lg * 8]);
#pragma unroll
      for (int nt = 0; nt < 2; ++nt)
        b[nt] = *reinterpret_cast<const bf16x8*>(&Bs[(wn * 32 + nt * 16 + lr) * LDP + ks * 32 + lg * 8]);
#pragma unroll
      for (int mt = 0; mt < 2; ++mt)
#pragma unroll
        for (int nt = 0; nt < 2; ++nt)
          acc[mt][nt] = __builtin_amdgcn_mfma_f32_16x16x32_bf16(a[mt], b[nt], acc[mt][nt], 0, 0, 0);
    }
  }
#pragma unroll
  for (int mt = 0; mt < 2; ++mt) {
    int row = bm * 64 + wm * 32 + mt * 16 + lg * 4;
#pragma unroll
    for (int nt = 0; nt < 2; ++nt) {
      int col = bn * 64 + wn * 32 + nt * 16 + lr;
#pragma unroll
      for (int r = 0; r < 4; ++r)
        QK[(row + r) * HW + col] = __float2bfloat16(acc[mt][nt][r]);
    }
  }
}

// ---------------- Kernel 3: barrier-free scores + per-lane online LSE --------
// grid (16 q-tiles of 128, 12 heads, 4 k-splits) = 768 blocks (3/CU).
// Wave w owns q rows q0+w*32..+31. NO LDS, NO barriers: both A and B MFMA
// fragments are contiguous 16B row spans of row-major QK -> direct dwordx4
// global loads (hit per-XCD L2; K working set/head = 256KB*12 = 3.1MB < 4MB).
// Each lane keeps private (m,l) over its k-subset (k = kc+nt*16+lr).
__global__ __launch_bounds__(256) void attn_kernel(
    const __hip_bfloat16* __restrict__ QK, float2* __restrict__ part) {
  const int t = threadIdx.x;
  const int wave = t >> 6, lane = t & 63;
  const int lr = lane & 15, lg = lane >> 4;
  const int q0 = blockIdx.x * 128, h = blockIdx.y, sp = blockIdx.z;
  const int k0 = sp * KPW;
  const int colQ = h * 64 + lg * 8;      // elem offset within a QK row (Q part)
  const int colK = DD + h * 64 + lg * 8; // K part

  // Q fragments: 4 direct loads, resident for the whole kernel
  bf16x8 aq[2][2];
#pragma unroll
  for (int mt = 0; mt < 2; ++mt)
#pragma unroll
    for (int z = 0; z < 2; ++z)
      aq[mt][z] = *reinterpret_cast<const bf16x8*>(
          QK + (q0 + wave * 32 + mt * 16 + lr) * HW + colQ + z * 32);

  float m[2][4], l[2][4];
#pragma unroll
  for (int mt = 0; mt < 2; ++mt)
#pragma unroll
    for (int r = 0; r < 4; ++r) { m[mt][r] = -3.0e38f; l[mt][r] = 0.0f; }

  for (int kc = k0; kc < k0 + KPW; kc += 64) {
    bf16x8 b[4][2];
#pragma unroll
    for (int nt = 0; nt < 4; ++nt)
#pragma unroll
      for (int z = 0; z < 2; ++z)
        b[nt][z] = *reinterpret_cast<const bf16x8*>(
            QK + (kc + nt * 16 + lr) * HW + colK + z * 32);

    f32x4 s[2][4] = {};
#pragma unroll
    for (int mt = 0; mt < 2; ++mt)
#pragma unroll
      for (int nt = 0; nt < 4; ++nt)
#pragma unroll
        for (int z = 0; z < 2; ++z)
          s[mt][nt] = __builtin_amdgcn_mfma_f32_16x16x32_bf16(aq[mt][z], b[nt][z], s[mt][nt], 0, 0, 0);

    // per-lane online update (scores already in base-2 units)
#pragma unroll
    for (int mt = 0; mt < 2; ++mt)
#pragma unroll
      for (int r = 0; r < 4; ++r) {
        float v0 = s[mt][0][r], v1 = s[mt][1][r], v2 = s[mt][2][r], v3 = s[mt][3][r];
        float cm = fmaxf(fmaxf(v0, v1), fmaxf(v2, v3));
        float mn = fmaxf(m[mt][r], cm);
        float p = exp2g(v0 - mn) + exp2g(v1 - mn) +
                  exp2g(v2 - mn) + exp2g(v3 - mn);
        l[mt][r] = l[mt][r] * exp2g(m[mt][r] - mn) + p;
        m[mt][r] = mn;
      }
  }
  // butterfly merge across the 16 lr-lanes (lg bits untouched)
#pragma unroll
  for (int msk = 1; msk <= 8; msk <<= 1) {
#pragma unroll
    for (int mt = 0; mt < 2; ++mt)
#pragma unroll
      for (int r = 0; r < 4; ++r) {
        float mo = __shfl_xor(m[mt][r], msk);
        float lo = __shfl_xor(l[mt][r], msk);
        float mn = fmaxf(m[mt][r], mo);
        l[mt][r] = l[mt][r] * exp2g(m[mt][r] - mn) + lo * exp2g(mo - mn);
        m[mt][r] = mn;
      }
  }
  if (lr == 0) {
#pragma unroll
    for (int mt = 0; mt < 2; ++mt)
#pragma unroll
      for (int r = 0; r < 4; ++r) {
        int q = q0 + wave * 32 + mt * 16 + lg * 4 + r;
        part[(sp * HH + h) * NN + q] = make_float2(m[mt][r], l[mt][r]);
      }
  }
}

// ---------------- Kernel 4: merge splits + global sum (single block) ---------
// One block of 1024 threads; direct store to out -> no memset dispatch needed.
__global__ __launch_bounds__(1024) void reduce_kernel(
    const float2* __restrict__ part, float* __restrict__ out) {
  const int t = threadIdx.x;
  float acc = 0.0f;
  for (int row = t; row < HH * NN; row += 1024) {
    float2 p0 = part[row];
    float2 p1 = part[24576 + row];
    float2 p2 = part[49152 + row];
    float2 p3 = part[73728 + row];
    float m = fmaxf(fmaxf(p0.x, p1.x), fmaxf(p2.x, p3.x));
    float l = p0.y * exp2g(p0.x - m) + p1.y * exp2g(p1.x - m) +
              p2.y * exp2g(p2.x - m) + p3.y * exp2g(p3.x - m);
    acc += m + log2g(l);                 // base-2 lse
  }
#pragma unroll
  for (int msk = 1; msk <= 32; msk <<= 1)
    acc += __shfl_xor(acc, msk);
  __shared__ float wsum[16];
  if ((t & 63) == 0) wsum[t >> 6] = acc;
  __syncthreads();
  if (t == 0) {
    float s = 0.0f;
#pragma unroll
    for (int i = 0; i < 16; ++i) s += wsum[i];
    out[0] = -5.545177444479562f * s;    // -(1/beta)*ln2 * sum(base2-lse)
  }
}

// ---------------- launch -----------------------------------------------------
extern "C" void kernel_launch(void* const* d_in, const int* in_sizes, int n_in,
                              void* d_out, int out_size, void* d_ws, size_t ws_size,
                              hipStream_t stream) {
  const float* g  = (const float*)d_in[0];
  const float* Wq = (const float*)d_in[1];
  const float* Wk = (const float*)d_in[2];
  float* out = (float*)d_out;

  __hip_bfloat16* gB = (__hip_bfloat16*)d_ws;        // [2048][768]  (3.1 MB)
  __hip_bfloat16* wB = gB + G_ELEMS;                 // [1536][768]  (2.4 MB)
  __hip_bfloat16* QK = wB + 2 * W1_ELEMS;            // [2048][1536] (6.3 MB)
  // partials alias gB: gB is dead after proj_kernel (stream-ordered); 786 KB.
  float2* part = (float2*)gB;

  convert_kernel<<<2688, 256, 0, stream>>>(g, Wq, Wk, gB, wB);
  proj_kernel<<<dim3(32, 24), 256, 0, stream>>>(gB, wB, QK);
  attn_kernel<<<dim3(16, HH, SPLITS), 256, 0, stream>>>(QK, part);
  reduce_kernel<<<1, 1024, 0, stream>>>(part, out);
}

// Round 5
// 94.682 us; speedup vs baseline: 1.2738x; 1.2738x over previous
//
#include <hip/hip_runtime.h>
#include <hip/hip_bf16.h>

// N=2048, D=768, H=12, Y=64. W = [Wq;Wk] as [1536][768].
#define NN 2048
#define DD 768
#define HH 12
#define HW 1536
#define G_ELEMS (NN*DD)           // 1572864
#define W1_ELEMS (HH*64*DD)       // 589824
#define SPLITS 4
#define KPW (NN/SPLITS)           // 512 k-rows per split
#define NCH (KPW/64)              // 8 chunks per split

typedef __attribute__((ext_vector_type(8))) short bf16x8;
typedef __attribute__((ext_vector_type(4))) float f32x4;

// native v_exp_f32 / v_log_f32 (both base-2). __exp2f/__log2f collide with
// glibc math.h reserved identifiers under -x hip.
__device__ __forceinline__ float exp2g(float x) { return __builtin_amdgcn_exp2f(x); }
__device__ __forceinline__ float log2g(float x) { return __builtin_amdgcn_logf(x); }

// ---------------- Kernel 1: fp32 -> bf16 convert (+ zero out) ----------------
// Fold beta*log2(e) = 0.125*1.4426950408889634 into Wq -> scores in base-2.
#define QSCALE 0.18033688011112042f
__global__ __launch_bounds__(256) void convert_kernel(
    const float* __restrict__ g, const float* __restrict__ Wq,
    const float* __restrict__ Wk, __hip_bfloat16* __restrict__ gB,
    __hip_bfloat16* __restrict__ wB, float* __restrict__ out) {
  if (blockIdx.x == 0 && threadIdx.x == 0) out[0] = 0.0f;  // kills memset dispatch
  int base = (blockIdx.x * 256 + threadIdx.x) * 4;
  float4 v;
  __hip_bfloat16* dst;
  if (base < G_ELEMS) {
    v = *reinterpret_cast<const float4*>(g + base);
    dst = gB + base;
  } else if (base < G_ELEMS + W1_ELEMS) {
    int o = base - G_ELEMS;
    v = *reinterpret_cast<const float4*>(Wq + o);
    v.x *= QSCALE; v.y *= QSCALE; v.z *= QSCALE; v.w *= QSCALE;
    dst = wB + o;
  } else {
    int o = base - (G_ELEMS + W1_ELEMS);
    v = *reinterpret_cast<const float4*>(Wk + o);
    dst = wB + W1_ELEMS + o;
  }
  __hip_bfloat16 h0 = __float2bfloat16(v.x), h1 = __float2bfloat16(v.y);
  __hip_bfloat16 h2 = __float2bfloat16(v.z), h3 = __float2bfloat16(v.w);
  ushort4 u;
  u.x = *reinterpret_cast<unsigned short*>(&h0);
  u.y = *reinterpret_cast<unsigned short*>(&h1);
  u.z = *reinterpret_cast<unsigned short*>(&h2);
  u.w = *reinterpret_cast<unsigned short*>(&h3);
  *reinterpret_cast<ushort4*>(dst) = u;
}

// ---------------- Kernel 2: QK projection GEMM, double-buffered --------------
// C[2048][1536] = gB[2048][768] * wB[1536][768]^T
// 64x64 tile, BK=64, grid (32,24)=768 (3/CU). One barrier per kt:
// loads(kt+1) -> compute(kt) -> ds_write(kt+1) -> barrier.
#define LDP 72   // 64 + 8 pad -> 2-way max on frag reads (free, m136)
__global__ __launch_bounds__(256) void proj_kernel(
    const __hip_bfloat16* __restrict__ gB, const __hip_bfloat16* __restrict__ wB,
    __hip_bfloat16* __restrict__ QK) {
  __shared__ __align__(16) __hip_bfloat16 As[2][64 * LDP];
  __shared__ __align__(16) __hip_bfloat16 Bs[2][64 * LDP];
  const int t = threadIdx.x;
  const int wave = t >> 6, lane = t & 63;
  const int lr = lane & 15, lg = lane >> 4;
  const int wm = wave & 1, wn = wave >> 1;
  const int bm = blockIdx.x, bn = blockIdx.y;
  const int r0 = t >> 3, s0 = (t & 7) * 8;            // chunk 0 coords
  const int r1 = (t + 256) >> 3, s1 = s0;             // chunk 1 coords

  f32x4 acc[2][2] = {};

  // prologue: stage kt=0
  {
    *reinterpret_cast<uint4*>(&As[0][r0 * LDP + s0]) =
        *reinterpret_cast<const uint4*>(gB + (bm * 64 + r0) * DD + s0);
    *reinterpret_cast<uint4*>(&As[0][r1 * LDP + s1]) =
        *reinterpret_cast<const uint4*>(gB + (bm * 64 + r1) * DD + s1);
    *reinterpret_cast<uint4*>(&Bs[0][r0 * LDP + s0]) =
        *reinterpret_cast<const uint4*>(wB + (bn * 64 + r0) * DD + s0);
    *reinterpret_cast<uint4*>(&Bs[0][r1 * LDP + s1]) =
        *reinterpret_cast<const uint4*>(wB + (bn * 64 + r1) * DD + s1);
  }
  __syncthreads();

  for (int it = 0; it < 12; ++it) {
    const int cur = it & 1;
    uint4 na0, na1, nb0, nb1;
    if (it < 11) {
      int kt = (it + 1) * 64;
      na0 = *reinterpret_cast<const uint4*>(gB + (bm * 64 + r0) * DD + kt + s0);
      na1 = *reinterpret_cast<const uint4*>(gB + (bm * 64 + r1) * DD + kt + s1);
      nb0 = *reinterpret_cast<const uint4*>(wB + (bn * 64 + r0) * DD + kt + s0);
      nb1 = *reinterpret_cast<const uint4*>(wB + (bn * 64 + r1) * DD + kt + s1);
    }
#pragma unroll
    for (int ks = 0; ks < 2; ++ks) {
      bf16x8 a[2], b[2];
#pragma unroll
      for (int mt = 0; mt < 2; ++mt)
        a[mt] = *reinterpret_cast<const bf16x8*>(&As[cur][(wm * 32 + mt * 16 + lr) * LDP + ks * 32 + lg * 8]);
#pragma unroll
      for (int nt = 0; nt < 2; ++nt)
        b[nt] = *reinterpret_cast<const bf16x8*>(&Bs[cur][(wn * 32 + nt * 16 + lr) * LDP + ks * 32 + lg * 8]);
#pragma unroll
      for (int mt = 0; mt < 2; ++mt)
#pragma unroll
        for (int nt = 0; nt < 2; ++nt)
          acc[mt][nt] = __builtin_amdgcn_mfma_f32_16x16x32_bf16(a[mt], b[nt], acc[mt][nt], 0, 0, 0);
    }
    if (it < 11) {
      *reinterpret_cast<uint4*>(&As[cur ^ 1][r0 * LDP + s0]) = na0;
      *reinterpret_cast<uint4*>(&As[cur ^ 1][r1 * LDP + s1]) = na1;
      *reinterpret_cast<uint4*>(&Bs[cur ^ 1][r0 * LDP + s0]) = nb0;
      *reinterpret_cast<uint4*>(&Bs[cur ^ 1][r1 * LDP + s1]) = nb1;
      __syncthreads();
    }
  }
#pragma unroll
  for (int mt = 0; mt < 2; ++mt) {
    int row = bm * 64 + wm * 32 + mt * 16 + lg * 4;
#pragma unroll
    for (int nt = 0; nt < 2; ++nt) {
      int col = bn * 64 + wn * 32 + nt * 16 + lr;
#pragma unroll
      for (int r = 0; r < 4; ++r)
        QK[(row + r) * HW + col] = __float2bfloat16(acc[mt][nt][r]);
    }
  }
}

// ---------------- Kernel 3: scores + per-lane online LSE, dbuf K -------------
// grid (16 q-tiles of 128, 12 heads, 4 k-splits) = 768 blocks (3/CU).
// Wave w owns q rows q0+w*32..+31. Q frags loaded ONCE direct from global;
// K staged in double-buffered LDS shared by all 4 waves, ONE barrier/chunk.
// Each lane keeps private (m,l) over its k-subset (k = kc+nt*16+lr).
#define LDA 72
__global__ __launch_bounds__(256) void attn_kernel(
    const __hip_bfloat16* __restrict__ QK, float2* __restrict__ part) {
  __shared__ __align__(16) __hip_bfloat16 Ks[2][64 * LDA];
  const int t = threadIdx.x;
  const int wave = t >> 6, lane = t & 63;
  const int lr = lane & 15, lg = lane >> 4;
  const int q0 = blockIdx.x * 128, h = blockIdx.y, sp = blockIdx.z;
  const int k0 = sp * KPW;
  const int r0 = t >> 3, s0 = (t & 7) * 8;            // chunk coords (2/thread)
  const int r1 = (t + 256) >> 3, s1 = s0;
  const int colK = DD + h * 64;

  // Q fragments: 4 direct loads, resident for the whole kernel
  bf16x8 aq[2][2];
#pragma unroll
  for (int mt = 0; mt < 2; ++mt)
#pragma unroll
    for (int z = 0; z < 2; ++z)
      aq[mt][z] = *reinterpret_cast<const bf16x8*>(
          QK + (q0 + wave * 32 + mt * 16 + lr) * HW + h * 64 + z * 32 + lg * 8);

  // prologue: stage chunk 0
  *reinterpret_cast<uint4*>(&Ks[0][r0 * LDA + s0]) =
      *reinterpret_cast<const uint4*>(QK + (k0 + r0) * HW + colK + s0);
  *reinterpret_cast<uint4*>(&Ks[0][r1 * LDA + s1]) =
      *reinterpret_cast<const uint4*>(QK + (k0 + r1) * HW + colK + s1);
  __syncthreads();

  float m[2][4], l[2][4];
#pragma unroll
  for (int mt = 0; mt < 2; ++mt)
#pragma unroll
    for (int r = 0; r < 4; ++r) { m[mt][r] = -3.0e38f; l[mt][r] = 0.0f; }

  for (int ci = 0; ci < NCH; ++ci) {
    const int cur = ci & 1;
    uint4 n0, n1;
    if (ci < NCH - 1) {
      int kc = k0 + (ci + 1) * 64;
      n0 = *reinterpret_cast<const uint4*>(QK + (kc + r0) * HW + colK + s0);
      n1 = *reinterpret_cast<const uint4*>(QK + (kc + r1) * HW + colK + s1);
    }
    bf16x8 b[4][2];
#pragma unroll
    for (int nt = 0; nt < 4; ++nt)
#pragma unroll
      for (int z = 0; z < 2; ++z)
        b[nt][z] = *reinterpret_cast<const bf16x8*>(&Ks[cur][(nt * 16 + lr) * LDA + z * 32 + lg * 8]);

    f32x4 s[2][4] = {};
#pragma unroll
    for (int mt = 0; mt < 2; ++mt)
#pragma unroll
      for (int nt = 0; nt < 4; ++nt)
#pragma unroll
        for (int z = 0; z < 2; ++z)
          s[mt][nt] = __builtin_amdgcn_mfma_f32_16x16x32_bf16(aq[mt][z], b[nt][z], s[mt][nt], 0, 0, 0);

    // per-lane online update (scores already in base-2 units)
#pragma unroll
    for (int mt = 0; mt < 2; ++mt)
#pragma unroll
      for (int r = 0; r < 4; ++r) {
        float v0 = s[mt][0][r], v1 = s[mt][1][r], v2 = s[mt][2][r], v3 = s[mt][3][r];
        float cm = fmaxf(fmaxf(v0, v1), fmaxf(v2, v3));
        float mn = fmaxf(m[mt][r], cm);
        float p = exp2g(v0 - mn) + exp2g(v1 - mn) +
                  exp2g(v2 - mn) + exp2g(v3 - mn);
        l[mt][r] = l[mt][r] * exp2g(m[mt][r] - mn) + p;
        m[mt][r] = mn;
      }
    if (ci < NCH - 1) {
      *reinterpret_cast<uint4*>(&Ks[cur ^ 1][r0 * LDA + s0]) = n0;
      *reinterpret_cast<uint4*>(&Ks[cur ^ 1][r1 * LDA + s1]) = n1;
      __syncthreads();
    }
  }
  // butterfly merge across the 16 lr-lanes (lg bits untouched)
#pragma unroll
  for (int msk = 1; msk <= 8; msk <<= 1) {
#pragma unroll
    for (int mt = 0; mt < 2; ++mt)
#pragma unroll
      for (int r = 0; r < 4; ++r) {
        float mo = __shfl_xor(m[mt][r], msk);
        float lo = __shfl_xor(l[mt][r], msk);
        float mn = fmaxf(m[mt][r], mo);
        l[mt][r] = l[mt][r] * exp2g(m[mt][r] - mn) + lo * exp2g(mo - mn);
        m[mt][r] = mn;
      }
  }
  if (lr == 0) {
#pragma unroll
    for (int mt = 0; mt < 2; ++mt)
#pragma unroll
      for (int r = 0; r < 4; ++r) {
        int q = q0 + wave * 32 + mt * 16 + lg * 4 + r;
        part[(sp * HH + h) * NN + q] = make_float2(m[mt][r], l[mt][r]);
      }
  }
}

// ---------------- Kernel 4: merge splits + global sum ------------------------
// 24 blocks x 1024 thr, one row each; out was zeroed by convert_kernel.
__global__ __launch_bounds__(1024) void reduce_kernel(
    const float2* __restrict__ part, float* __restrict__ out) {
  const int t = threadIdx.x;
  const int row = blockIdx.x * 1024 + t;         // 0..24575 = (h*2048+q)
  float2 p0 = part[row];
  float2 p1 = part[24576 + row];
  float2 p2 = part[49152 + row];
  float2 p3 = part[73728 + row];
  float mm = fmaxf(fmaxf(p0.x, p1.x), fmaxf(p2.x, p3.x));
  float ll = p0.y * exp2g(p0.x - mm) + p1.y * exp2g(p1.x - mm) +
             p2.y * exp2g(p2.x - mm) + p3.y * exp2g(p3.x - mm);
  float lse = mm + log2g(ll);                    // base-2 lse
#pragma unroll
  for (int msk = 1; msk <= 32; msk <<= 1)
    lse += __shfl_xor(lse, msk);
  __shared__ float wsum[16];
  if ((t & 63) == 0) wsum[t >> 6] = lse;
  __syncthreads();
  if (t == 0) {
    float s = 0.0f;
#pragma unroll
    for (int i = 0; i < 16; ++i) s += wsum[i];
    atomicAdd(out, -5.545177444479562f * s);     // -(1/beta)*ln2 * sum(lse2)
  }
}

// ---------------- launch -----------------------------------------------------
extern "C" void kernel_launch(void* const* d_in, const int* in_sizes, int n_in,
                              void* d_out, int out_size, void* d_ws, size_t ws_size,
                              hipStream_t stream) {
  const float* g  = (const float*)d_in[0];
  const float* Wq = (const float*)d_in[1];
  const float* Wk = (const float*)d_in[2];
  float* out = (float*)d_out;

  __hip_bfloat16* gB = (__hip_bfloat16*)d_ws;        // [2048][768]  (3.1 MB)
  __hip_bfloat16* wB = gB + G_ELEMS;                 // [1536][768]  (2.4 MB)
  __hip_bfloat16* QK = wB + 2 * W1_ELEMS;            // [2048][1536] (6.3 MB)
  // partials alias gB: gB is dead after proj_kernel (stream-ordered); 786 KB.
  float2* part = (float2*)gB;

  convert_kernel<<<2688, 256, 0, stream>>>(g, Wq, Wk, gB, wB, out);
  proj_kernel<<<dim3(32, 24), 256, 0, stream>>>(gB, wB, QK);
  attn_kernel<<<dim3(16, HH, SPLITS), 256, 0, stream>>>(QK, part);
  reduce_kernel<<<24, 1024, 0, stream>>>(part, out);
}